// Round 7
// baseline (93.138 us; speedup 1.0000x reference)
//
#include <hip/hip_runtime.h>
#include <hip/hip_bf16.h>
#include <cstdint>

#define BATCH 8192
#define DIM   128
#define MARGIN 1.0f

typedef __attribute__((ext_vector_type(8))) short short8;
typedef __attribute__((ext_vector_type(4))) float f32x4;
typedef __attribute__((ext_vector_type(4))) int   i32x4;

// async 16B global -> LDS (LDS dst = wave-uniform base + lane*16)
__device__ __forceinline__ void async_copy16(const void* g, void* lds) {
    __builtin_amdgcn_global_load_lds(
        (const __attribute__((address_space(1))) unsigned int*)g,
        (__attribute__((address_space(3))) unsigned int*)lds, 16, 0, 0);
}

// ---------------------------------------------------------------------------
// Kernel 1: fp32 -> bf16 convert, per-row squared norms (fp32-exact),
// init hp2 (max-accum, 0) / hn2 (min-accum, +inf).
// ---------------------------------------------------------------------------
__global__ __launch_bounds__(256) void bhtl_prep(
    const float* __restrict__ emb,
    __hip_bfloat16* __restrict__ Ebf,
    float* __restrict__ sq,
    unsigned* __restrict__ hp2,
    unsigned* __restrict__ hn2)
{
    const int w   = threadIdx.x >> 6;
    const int l   = threadIdx.x & 63;
    const int row = blockIdx.x * 4 + w;
    const float2 e = ((const float2*)(emb + row * DIM))[l];
    __hip_bfloat162 h2;
    h2.x = __float2bfloat16(e.x);
    h2.y = __float2bfloat16(e.y);
    ((__hip_bfloat162*)(Ebf + row * DIM))[l] = h2;
    float s = e.x * e.x + e.y * e.y;
    #pragma unroll
    for (int d = 1; d < 64; d <<= 1) s += __shfl_xor(s, d, 64);
    if (l == 0) {
        sq[row]  = s;
        hp2[row] = 0u;           // max accumulator (non-negative domain)
        hn2[row] = 0x7F800000u;  // +inf (min accumulator)
    }
}

// ---------------------------------------------------------------------------
// Kernel 2: fused E @ E^T + hardest-pos/neg selection.
// 512 blocks = 64 row-tiles x 8 col-splits, 256 threads (4 waves).
// Per block: 128 rows x 1024 cols, 16 chunks of 64 cols.
// LDS 40 KB/block -> 4 blocks/CU (vs R6's 2): B dbuf 2x16 KB + sq/lab 8 KB.
// B staged via global_load_lds w=16, XOR swizzle on the GLOBAL side
//   (LDS unit (col,u) holds global 16B-chunk u^(col&7); fragment reads at
//   swz=(kc*4+q)^(ln&7) -> 8 lanes per bank-quad, phase-uniform = b128 floor).
// Column sq/labels staged to LDS once: hot loop has NO global loads except
//   staging, so each barrier's vmcnt drain waits only on prefetch.
// A fragments in registers (transposed MFMA: acc = mfma(B, A), lane (q,ln)
//   elem r -> row = rowbase+m*16+ln, col = jb+n*16+q*4+r; validated R4-R6).
// Atomics fire-and-forget, NO fence (R5 lesson).
// ---------------------------------------------------------------------------
__global__ __launch_bounds__(256, 4) void bhtl_main(
    const __hip_bfloat16* __restrict__ Ebf,
    const float* __restrict__ sq,
    const int* __restrict__ labels,
    unsigned* __restrict__ hp2,
    unsigned* __restrict__ hn2)
{
    __shared__ __align__(16) unsigned short B_s[2][8192];   // 2 x 16 KB
    __shared__ __align__(16) float sq_s[1024];              // 4 KB
    __shared__ __align__(16) int   lab_s[1024];             // 4 KB

    const int tid  = threadIdx.x;
    const int w    = tid >> 6;
    const int lane = tid & 63;
    const int q    = lane >> 4;
    const int ln   = lane & 15;
    const int rt   = blockIdx.x >> 3;          // 0..63 row tile
    const int js   = blockIdx.x & 7;           // 0..7 col split
    const int rowbase = rt * 128 + w * 32;
    const int jbase0  = js * 1024;

    // ---- stage a 64-col B chunk: 1024 16B-units; wave w does [w*256,+256) ----
    auto stage = [&](int buf, int chunk) {
        const int jb = jbase0 + chunk * 64;
        #pragma unroll
        for (int c = 0; c < 4; ++c) {
            int U   = w * 256 + c * 64 + lane;   // unit in chunk
            int col = U >> 4;                    // 0..63
            int u   = U & 15;
            int j   = u ^ (col & 7);             // swizzled source 16B-chunk
            async_copy16(Ebf + (size_t)(jb + col) * DIM + j * 8,
                         &B_s[buf][(w * 256 + c * 64) * 8]);
        }
    };

    // ---- stage column sq/labels for this block's 1024 cols (once) ----
    {
        int U = w * 64 + lane;                   // 0..255, 4 f32 each
        async_copy16(sq     + jbase0 + U * 4, &sq_s[w * 256]);
        async_copy16(labels + jbase0 + U * 4, &lab_s[w * 256]);
    }

    // ---- A fragments (32 rows/wave, K=128) + row metadata ----
    short8 af[2][4];
    float  sqi[2];
    int    labi[2];
    #pragma unroll
    for (int m = 0; m < 2; ++m) {
        const int row = rowbase + m * 16 + ln;
        #pragma unroll
        for (int kc = 0; kc < 4; ++kc)
            af[m][kc] = *(const short8*)(Ebf + (size_t)row * DIM + kc * 32 + q * 8);
        sqi[m]  = sq[row];
        labi[m] = labels[row];
    }

    float mp[2] = {-INFINITY, -INFINITY};
    float mn[2] = { INFINITY,  INFINITY};

    stage(0, 0);
    __syncthreads();                             // chunk 0 + sq/lab staged

    #pragma unroll 2
    for (int ch = 0; ch < 16; ++ch) {
        const int buf = ch & 1;
        if (ch < 15) stage(buf ^ 1, ch + 1);     // prefetch next chunk

        #pragma unroll
        for (int n = 0; n < 4; ++n) {
            const int cloc = ch * 64 + n * 16;   // block-local column base
            short8 bfr[4];
            #pragma unroll
            for (int kc = 0; kc < 4; ++kc)
                bfr[kc] = *(const short8*)(
                    &B_s[buf][((n * 16 + ln) * 16 + (((kc * 4 + q) ^ (ln & 7)))) * 8]);
            f32x4 sqj  = *(const f32x4*)(&sq_s [cloc + q * 4]);   // broadcast, free
            i32x4 labj = *(const i32x4*)(&lab_s[cloc + q * 4]);

            f32x4 acc[2];
            const f32x4 zero = {0.f, 0.f, 0.f, 0.f};
            acc[0] = zero; acc[1] = zero;
            #pragma unroll
            for (int kc = 0; kc < 4; ++kc)
                #pragma unroll
                for (int m = 0; m < 2; ++m)
                    acc[m] = __builtin_amdgcn_mfma_f32_16x16x32_bf16(
                        bfr[kc], af[m][kc], acc[m], 0, 0, 0);     // transposed

            #pragma unroll
            for (int m = 0; m < 2; ++m)
                #pragma unroll
                for (int r = 0; r < 4; ++r) {
                    float val = fmaf(-2.0f, acc[m][r], sqj[r]);
                    bool same = (labi[m] == labj[r]);
                    mp[m] = fmaxf(mp[m], same ? val : -INFINITY);
                    mn[m] = fminf(mn[m], same ? INFINITY : val);
                }
        }
        __syncthreads();   // next chunk staged; all waves done with buf
    }

    // ---- reduce over the 4 q-lanes sharing each row, then atomics ----
    #pragma unroll
    for (int m = 0; m < 2; ++m) {
        float a = mp[m], b = mn[m];
        a = fmaxf(a, __shfl_xor(a, 16, 64));
        a = fmaxf(a, __shfl_xor(a, 32, 64));
        b = fminf(b, __shfl_xor(b, 16, 64));
        b = fminf(b, __shfl_xor(b, 32, 64));
        if (q == 0) {
            const int row = rowbase + m * 16 + ln;
            atomicMax(&hp2[row], __float_as_uint(fmaxf(sqi[m] + a, 0.0f)));
            atomicMin(&hn2[row], __float_as_uint(fmaxf(sqi[m] + b, 0.0f)));
        }
    }
}

// ---------------------------------------------------------------------------
// Kernel 3: per-anchor loss + mean. Single block, deterministic output.
// ---------------------------------------------------------------------------
__global__ __launch_bounds__(1024) void bhtl_final(
    const unsigned* __restrict__ hp2,
    const unsigned* __restrict__ hn2,
    float* __restrict__ out)
{
    __shared__ float red[16];
    float sum = 0.f;
    for (int i = threadIdx.x; i < BATCH; i += 1024) {
        float hp = sqrtf(__uint_as_float(hp2[i]));
        float hn = sqrtf(__uint_as_float(hn2[i]));
        sum += fmaxf(hp - hn + MARGIN, 0.f);
    }
    #pragma unroll
    for (int d = 1; d < 64; d <<= 1) sum += __shfl_xor(sum, d, 64);
    int wv = threadIdx.x >> 6;
    if ((threadIdx.x & 63) == 0) red[wv] = sum;
    __syncthreads();
    if (threadIdx.x < 64) {
        float v = (threadIdx.x < 16) ? red[threadIdx.x] : 0.f;
        #pragma unroll
        for (int d = 1; d < 16; d <<= 1) v += __shfl_xor(v, d, 64);
        if (threadIdx.x == 0) out[0] = v / (float)BATCH;
    }
}

// ---------------------------------------------------------------------------
extern "C" void kernel_launch(void* const* d_in, const int* in_sizes, int n_in,
                              void* d_out, int out_size, void* d_ws, size_t ws_size,
                              hipStream_t stream)
{
    const float* emb    = (const float*)d_in[0];
    const int*   labels = (const int*)d_in[1];
    float*       out    = (float*)d_out;

    char* ws = (char*)d_ws;
    __hip_bfloat16* Ebf = (__hip_bfloat16*)ws;                        // 2 MiB
    float*    sq   = (float*)   (ws + 2 * 1024 * 1024);               // 32 KiB
    unsigned* hp2  = (unsigned*)(ws + 2 * 1024 * 1024 + 32 * 1024);   // 32 KiB
    unsigned* hn2  = (unsigned*)(ws + 2 * 1024 * 1024 + 64 * 1024);   // 32 KiB

    bhtl_prep<<<BATCH / 4, 256, 0, stream>>>(emb, Ebf, sq, hp2, hn2);
    bhtl_main<<<512, 256, 0, stream>>>(Ebf, sq, labels, hp2, hn2);
    bhtl_final<<<1, 1024, 0, stream>>>(hp2, hn2, out);
}